// Round 3
// baseline (15587.642 us; speedup 1.0000x reference)
//
#include <hip/hip_runtime.h>
#include <hip/hip_bf16.h>

#define N_  64
#define T_  512
#define D_  512
#define H_  512
#define FH  2048   // 4H
#define K1  1024   // hi|lo packed columns
#define NWG 256
#define NSTEPWG 128
#define BLK 256

typedef __attribute__((ext_vector_type(4))) float f32x4;
typedef __attribute__((ext_vector_type(8))) short bf16x8;

__device__ __forceinline__ unsigned short f2bf(float f) {
  unsigned u = __float_as_uint(f);
  return (unsigned short)((u + 0x7FFFu + ((u >> 16) & 1u)) >> 16);
}
__device__ __forceinline__ float bf2f(unsigned short s) {
  return __uint_as_float(((unsigned)s) << 16);
}

__device__ __forceinline__ void gl_lds16(const void* g, void* l) {
  __builtin_amdgcn_global_load_lds(
      (const __attribute__((address_space(1))) void*)g,
      (__attribute__((address_space(3))) void*)l, 16, 0, 0);
}

// Monotonic-generation grid barrier (agent scope). Spin-capped: a logic bug
// produces wrong data (detectable) instead of a hang.
template <int SLP>
__device__ __forceinline__ void gbar(unsigned* cnt, unsigned* rel, unsigned gen,
                                     unsigned nwg) {
  __syncthreads();
  if (threadIdx.x == 0) {
    unsigned old = __hip_atomic_fetch_add(cnt, 1u, __ATOMIC_ACQ_REL,
                                          __HIP_MEMORY_SCOPE_AGENT);
    if (old == gen * nwg - 1u) {
      __hip_atomic_store(rel, gen, __ATOMIC_RELEASE, __HIP_MEMORY_SCOPE_AGENT);
    } else {
      int guard = 0;
      while (__hip_atomic_load(rel, __ATOMIC_ACQUIRE,
                               __HIP_MEMORY_SCOPE_AGENT) < gen) {
        __builtin_amdgcn_s_sleep(SLP);
        if (++guard > (1 << 22)) break;
      }
    }
  }
  __syncthreads();
}

// K'=1536 3-pass split-bf16 GEMM mapping:
//   A' = [Ahi | Ahi | Alo], B' = [Bhi | Blo | Bhi], both stored as [hi(512)|lo(512)].
//   A src col = (kk<16 ? kk : kk-16)*32 ; B src row = (kk<32 ? kk : kk-32)*32.
// LWH=true: Wh slice persistent in 128KiB dynamic LDS (XOR-swizzled).
// LWH=false: fallback — read Wh fragments from global each step.
template <bool LWH>
__global__ void __launch_bounds__(BLK, 1)
lstm_persistent(const float* __restrict__ x, const float* __restrict__ h0,
                const float* __restrict__ Wx, const float* __restrict__ Wh,
                const float* __restrict__ b, float* __restrict__ out,
                void* __restrict__ ws, int Tc) {
  extern __shared__ char dynLds[];               // 128 KiB Wh slice (LWH only)
  __shared__ __align__(16) short Asm[128 * 32];  // 8 KiB
  __shared__ __align__(16) short Bsm[128 * 32];  // 8 KiB
  __shared__ float glds[4][16][16];              // 4 KiB gate staging

  char* wsb = (char*)ws;
  unsigned* cntF = (unsigned*)(wsb + 0);
  unsigned* relF = (unsigned*)(wsb + 64);
  unsigned* cntH = (unsigned*)(wsb + 128);
  unsigned* relH = (unsigned*)(wsb + 192);
  short* Wxt   = (short*)(wsb + 256);            // [2048][1024] bf16 (hi|lo), W^T
  short* Wht   = Wxt + (size_t)FH * K1;          // [2048][1024]
  short* hbuf0 = Wht + (size_t)FH * K1;          // [64][1024] bf16 (hi|lo)
  short* hbuf1 = hbuf0 + N_ * K1;
  float* cbuf  = (float*)(hbuf1 + N_ * K1);      // [64][512] f32
  short* xprim = (short*)(cbuf + N_ * H_);       // [Tc*64][1024] bf16 (hi|lo)
  float* xwxb  = (float*)(xprim + (size_t)Tc * N_ * K1); // [Tc*64][2048] f32

  const int tid = threadIdx.x;
  const int wg = blockIdx.x;
  const int gtid = wg * BLK + tid;
  const int lane = tid & 63;
  const int wv = tid >> 6;

  unsigned genF = 0, genH = 0;

  // ---- prep: split-transpose weights into [j][k_hi | k_lo] bf16 ----
  for (int idx = gtid; idx < 2 * D_ * FH; idx += NWG * BLK) {
    int m = idx >> 20;                 // 0 = Wx, 1 = Wh   (D_*FH = 1<<20)
    int rr = idx & ((1 << 20) - 1);
    int j = rr >> 9;
    int k = rr & 511;
    float v = (m ? Wh : Wx)[(size_t)k * FH + j];
    unsigned short hi = f2bf(v);
    unsigned short lo = f2bf(v - bf2f(hi));
    short* dst = m ? Wht : Wxt;
    dst[(size_t)j * K1 + k] = (short)hi;
    dst[(size_t)j * K1 + 512 + k] = (short)lo;
  }
  // ---- h0 -> hi/lo bf16, c = 0 ----
  for (int idx = gtid; idx < N_ * H_; idx += NWG * BLK) {
    int n = idx >> 9, k = idx & 511;
    float v = h0[idx];
    unsigned short hi = f2bf(v);
    unsigned short lo = f2bf(v - bf2f(hi));
    hbuf0[n * K1 + k] = (short)hi;
    hbuf0[n * K1 + 512 + k] = (short)lo;
    cbuf[idx] = 0.0f;
  }
  gbar<4>(cntF, relF, ++genF, NWG);

  // ---- step WGs: load persistent Wh slice into LDS (XOR-swizzled 16B units) ----
  if constexpr (LWH) {
    if (wg < NSTEPWG) {
      const int cg = wg >> 2;
      short* wl = (short*)dynLds;
      for (int u = tid; u < 64 * 128; u += BLK) {
        int lc = u >> 7, k16 = u & 127;
        int gc = ((lc >> 4) << 9) + cg * 16 + (lc & 15); // gate*512 + cg*16 + col
        int4 v = *(const int4*)(Wht + (size_t)gc * K1 + k16 * 8);
        *(int4*)(wl + lc * K1 + ((k16 ^ (lc & 7)) << 3)) = v;
      }
    }
    __syncthreads();
  }

  const int nCh = T_ / Tc;
  const int Mch = Tc * N_;
  const int wm = wv >> 1, wn = wv & 1;

  for (int ch = 0; ch < nCh; ++ch) {
    const int t0 = ch * Tc;

    // -------- x chunk -> hi/lo bf16, row m = tl*64 + n --------
    for (int idx = gtid; idx < Mch * D_; idx += NWG * BLK) {
      int mrow = idx >> 9, d = idx & 511;
      int tl = mrow >> 6, n = mrow & 63;
      float v = x[((size_t)n * T_ + (t0 + tl)) * D_ + d];
      unsigned short hi = f2bf(v);
      unsigned short lo = f2bf(v - bf2f(hi));
      xprim[(size_t)mrow * K1 + d] = (short)hi;
      xprim[(size_t)mrow * K1 + 512 + d] = (short)lo;
    }
    gbar<2>(cntF, relF, ++genF, NWG);

    // -------- phase 1: xwxb = x' @ Wx' + b  (128x128 tiles, K'=1536) --------
    const int nTiles = (Mch >> 7) * (FH >> 7);
    for (int tile = wg; tile < nTiles; tile += NWG) {
      int tm = tile >> 4, tn = tile & 15;
      int m0 = tm << 7, n0 = tn << 7;
      f32x4 acc[4][4];
      for (int i = 0; i < 4; ++i)
        for (int j = 0; j < 4; ++j) acc[i][j] = (f32x4){0.f, 0.f, 0.f, 0.f};
      for (int kk = 0; kk < 48; ++kk) {
        int ac = (kk < 16 ? kk : kk - 16) << 5;
        int bc = (kk < 32 ? kk : kk - 32) << 5;
        __syncthreads();
        {
          const short* sa =
              xprim + (size_t)(m0 + wv * 32 + (lane >> 2)) * K1 + ac + (lane & 3) * 8;
          gl_lds16(sa, Asm + (wv * 32) * 32);
          gl_lds16(sa + (size_t)16 * K1, Asm + (wv * 32 + 16) * 32);
          const short* sb =
              Wxt + (size_t)(n0 + wv * 32 + (lane >> 2)) * K1 + bc + (lane & 3) * 8;
          gl_lds16(sb, Bsm + (wv * 32) * 32);
          gl_lds16(sb + (size_t)16 * K1, Bsm + (wv * 32 + 16) * 32);
        }
        __syncthreads();
        bf16x8 af[4], bfr[4];
        for (int mi = 0; mi < 4; ++mi)
          af[mi] = *(const bf16x8*)(Asm + (wm * 64 + mi * 16 + (lane & 15)) * 32 +
                                    (lane >> 4) * 8);
        for (int ni = 0; ni < 4; ++ni)
          bfr[ni] = *(const bf16x8*)(Bsm + (wn * 64 + ni * 16 + (lane & 15)) * 32 +
                                     (lane >> 4) * 8);
        for (int mi = 0; mi < 4; ++mi)
          for (int ni = 0; ni < 4; ++ni)
            acc[mi][ni] = __builtin_amdgcn_mfma_f32_16x16x32_bf16(
                af[mi], bfr[ni], acc[mi][ni], 0, 0, 0);
      }
      for (int ni = 0; ni < 4; ++ni) {
        float bj = b[n0 + wn * 64 + ni * 16 + (lane & 15)];
        for (int mi = 0; mi < 4; ++mi) {
          int mg = m0 + wm * 64 + mi * 16 + ((lane >> 4) << 2);
          float* dst =
              xwxb + (size_t)mg * FH + n0 + wn * 64 + ni * 16 + (lane & 15);
          for (int r = 0; r < 4; ++r) dst[(size_t)r * FH] = acc[mi][ni][r] + bj;
        }
      }
    }
    gbar<2>(cntF, relF, ++genF, NWG);

    // -------- recurrent steps: 128 WGs, 1 barrier/step --------
    if (wg < NSTEPWG) {
      const int rb = wg & 3, cg = wg >> 2;
      const short* wl = (const short*)dynLds;
      const int lc = wv * 16 + (lane & 15);
      const int gcl = wv * 512 + cg * 16 + (lane & 15);  // global Wh' row (fallback)
      for (int tl = 0; tl < Tc; ++tl) {
        int tg = t0 + tl;
        const short* hc = (tg & 1) ? hbuf1 : hbuf0;
        short* hn = (tg & 1) ? hbuf0 : hbuf1;
        f32x4 acc0 = {0.f, 0.f, 0.f, 0.f};
        f32x4 acc1 = {0.f, 0.f, 0.f, 0.f};
        const short* arow =
            hc + (size_t)(rb * 16 + (lane & 15)) * K1 + (lane >> 4) * 8;
#pragma unroll
        for (int kk = 0; kk < 48; ++kk) {
          int ab = (kk < 16 ? kk : kk - 16) << 5;
          int bb = (kk < 32 ? kk : kk - 32) << 5;
          bf16x8 av = *(const bf16x8*)(arow + ab);
          bf16x8 bv;
          if constexpr (LWH) {
            int k16 = (bb >> 3) + (lane >> 4);
            bv = *(const bf16x8*)(wl + lc * K1 + ((k16 ^ (lc & 7)) << 3));
          } else {
            bv = *(const bf16x8*)(Wht + (size_t)gcl * K1 + bb + (lane >> 4) * 8);
          }
          if (kk & 1)
            acc1 = __builtin_amdgcn_mfma_f32_16x16x32_bf16(av, bv, acc1, 0, 0, 0);
          else
            acc0 = __builtin_amdgcn_mfma_f32_16x16x32_bf16(av, bv, acc0, 0, 0, 0);
        }
        f32x4 a = acc0 + acc1;
        for (int r = 0; r < 4; ++r)
          glds[wv][((lane >> 4) << 2) + r][lane & 15] = a[r];
        __syncthreads();
        {
          int row = tid >> 4, col = tid & 15;
          int n = rb * 16 + row, jh = cg * 16 + col;
          const float* xr = xwxb + ((size_t)tl * 64 + n) * FH + jh;
          float gi = glds[0][row][col] + xr[0];
          float gf = glds[1][row][col] + xr[512];
          float go = glds[2][row][col] + xr[1024];
          float gg = glds[3][row][col] + xr[1536];
          float si = 1.0f / (1.0f + __expf(-gi));
          float sf = 1.0f / (1.0f + __expf(-gf));
          float so = 1.0f / (1.0f + __expf(-go));
          float tg2 = tanhf(gg);
          float cn = sf * cbuf[n * H_ + jh] + si * tg2;
          cbuf[n * H_ + jh] = cn;
          float hv = so * tanhf(cn);
          out[((size_t)n * T_ + tg) * H_ + jh] = hv;
          unsigned short hi = f2bf(hv);
          unsigned short lo = f2bf(hv - bf2f(hi));
          hn[n * K1 + jh] = (short)hi;
          hn[n * K1 + 512 + jh] = (short)lo;
        }
        gbar<1>(cntH, relH, ++genH, NSTEPWG);
      }
    } else {
      genH += Tc;
    }
    gbar<4>(cntF, relF, ++genF, NWG);
  }
}

extern "C" void kernel_launch(void* const* d_in, const int* in_sizes, int n_in,
                              void* d_out, int out_size, void* d_ws, size_t ws_size,
                              hipStream_t stream) {
  (void)in_sizes; (void)n_in; (void)out_size;
  const float* x  = (const float*)d_in[0];
  const float* h0 = (const float*)d_in[1];
  const float* Wx = (const float*)d_in[2];
  const float* Wh = (const float*)d_in[3];
  const float* b  = (const float*)d_in[4];
  float* out = (float*)d_out;

  // ws: 256B barriers + 8MB weights + 2x128KB h + 128KB c + Tc*(128KB x' + 512KB xwxb)
  size_t fixed = 256 + 2 * (size_t)FH * K1 * 2 + 2 * (size_t)N_ * K1 * 2 +
                 (size_t)N_ * H_ * 4;
  size_t perTc = (size_t)N_ * K1 * 2 + (size_t)N_ * FH * 4;
  int Tc = 64;
  while (Tc > 1 && fixed + (size_t)Tc * perTc > ws_size) Tc >>= 1;

  (void)hipMemsetAsync(d_ws, 0, 256, stream);  // reset barrier counters every replay
  (void)hipFuncSetAttribute((const void*)lstm_persistent<true>,
                            hipFuncAttributeMaxDynamicSharedMemorySize, 131072);

  void* args[] = {(void*)&x, (void*)&h0, (void*)&Wx, (void*)&Wh,
                  (void*)&b, (void*)&out, (void*)&d_ws, (void*)&Tc};

  // Path A: cooperative launch of LDS-Wh kernel.
  hipError_t e = hipLaunchCooperativeKernel((void*)lstm_persistent<true>,
                                            dim3(NWG), dim3(BLK), args, 131072,
                                            stream);
  if (e != hipSuccess) {
    // Path B: plain launch of the same kernel (custom barrier only needs
    // co-residency, which 148 KiB LDS/WG -> 1 WG/CU x 256 CUs guarantees).
    (void)hipGetLastError();  // clear stale error so we don't double-launch
    lstm_persistent<true><<<dim3(NWG), dim3(BLK), 131072, stream>>>(
        x, h0, Wx, Wh, b, out, d_ws, Tc);
    e = hipGetLastError();
  }
  if (e != hipSuccess) {
    // Path C: fallback — Wh read from global, tiny static LDS only.
    (void)hipGetLastError();
    lstm_persistent<false><<<dim3(NWG), dim3(BLK), 0, stream>>>(
        x, h0, Wx, Wh, b, out, d_ws, Tc);
    (void)hipGetLastError();
  }
}